// Round 13
// baseline (11166.728 us; speedup 1.0000x reference)
//
#include <hip/hip_runtime.h>
#include <hip/hip_fp16.h>

#define BB 8
#define SS 2048
#define EE 1024
#define NHH 4
#define DHH 256

typedef _Float16 f16x2 __attribute__((ext_vector_type(2)));
typedef _Float16 f16x8 __attribute__((ext_vector_type(8)));
typedef float f32x4 __attribute__((ext_vector_type(4)));

__device__ __forceinline__ __half2 u2h2(unsigned int u) {
  union { unsigned int u; __half2 h; } c; c.u = u; return c.h;
}
__device__ __forceinline__ unsigned int h2u(__half2 h) {
  union { unsigned int u; __half2 h; } c; c.h = h; return c.u;
}

// ---------------------------------------------------------------------------
// Gates projection GEMM via MFMA f16 (round-10 verbatim, verified).
// Output: gx f16, layout [S][B][NH][4*DH] = [i f z o]
// ---------------------------------------------------------------------------
__global__ __launch_bounds__(256) void gates_gemm(
    const float* __restrict__ x, const float* __restrict__ conv_w,
    const float* __restrict__ conv_b,
    const float* __restrict__ fgw, const float* __restrict__ igw,
    const float* __restrict__ zgw, const float* __restrict__ ogw,
    __half* __restrict__ gx)
{
  __shared__ float Xs[8][11][33];
  __shared__ __half As[64][40];
  __shared__ __half Bs[64][40];

  const int tid = threadIdx.x;
  const int mt = blockIdx.x;
  const int nt = blockIdx.y;
  const int p  = blockIdx.z;
  const int h  = p >> 1, pair = p & 1;
  const int s0 = mt << 3;
  const int n0 = nt << 6;

  const float* W0 = pair ? zgw : fgw;
  const float* W1 = pair ? ogw : igw;

  const int w = tid >> 6, l = tid & 63;
  const int lrow = l & 15, kq = l >> 4;
  const int koff = kq << 3;

  f32x4 acc[4] = {};

  for (int d0 = 0; d0 < DHH; d0 += 32) {
    const int ebase = h * DHH + d0;

    if (pair == 0) {
      for (int i = tid; i < 8 * 11 * 32; i += 256) {
        int kk = i & 31, rest = i >> 5;
        int b = rest / 11, si = rest - b * 11;
        int sg = s0 - 3 + si;
        float v = 0.f;
        if (sg >= 0) v = x[((size_t)b * SS + sg) * EE + ebase + kk];
        Xs[b][si][kk] = v;
      }
      __syncthreads();
      for (int i = tid; i < 64 * 32; i += 256) {
        int kk = i & 31, r = i >> 5;
        int sl = r >> 3, b = r & 7;
        int e = ebase + kk;
        float xc = conv_b[e];
        xc = fmaf(Xs[b][sl + 0][kk], conv_w[0 * EE + e], xc);
        xc = fmaf(Xs[b][sl + 1][kk], conv_w[1 * EE + e], xc);
        xc = fmaf(Xs[b][sl + 2][kk], conv_w[2 * EE + e], xc);
        xc = fmaf(Xs[b][sl + 3][kk], conv_w[3 * EE + e], xc);
        float sg = 1.f / (1.f + __expf(-xc));
        As[r][kk] = __float2half(xc * sg);
      }
    } else {
      for (int i = tid; i < 64 * 32; i += 256) {
        int kk = i & 31, r = i >> 5;
        int sl = r >> 3, b = r & 7;
        As[r][kk] = __float2half(x[((size_t)b * SS + s0 + sl) * EE + ebase + kk]);
      }
    }
    for (int i = tid; i < 64 * 32; i += 256) {
      int k = i & 31, col = i >> 5;
      int o = n0 + col;
      const float* Wp = (o < 256) ? W0 : W1;
      int oo = o & 255;
      Bs[col][k] = __float2half(Wp[((size_t)h * DHH + oo) * DHH + d0 + k]);
    }
    __syncthreads();

    f16x8 bfrag = *(const f16x8*)&Bs[w * 16 + lrow][koff];
#pragma unroll
    for (int mtl = 0; mtl < 4; ++mtl) {
      f16x8 afrag = *(const f16x8*)&As[mtl * 16 + lrow][koff];
      acc[mtl] = __builtin_amdgcn_mfma_f32_16x16x32_f16(afrag, bfrag, acc[mtl], 0, 0, 0);
    }
    __syncthreads();
  }

#pragma unroll
  for (int mtl = 0; mtl < 4; ++mtl) {
#pragma unroll
    for (int j = 0; j < 4; ++j) {
      int row_loc = mtl * 16 + kq * 4 + j;
      int grow = s0 * 8 + row_loc;
      int colg = n0 + w * 16 + lrow;
      gx[(size_t)grow * 4096 + h * 1024 + pair * 512 + colg] = __float2half(acc[mtl][j]);
    }
  }
}

// ---------------------------------------------------------------------------
// sLSTM scan v5: MFMA matvec, minimal LDS streaming.
// One WG (512 thr, 8 waves) per chain. Wave w owns cols [w*128, w*128+128)
// = 8 N-tiles; tiles 0..6 register-resident B-fragments (224 dwords -> AGPR,
// consumed directly by MFMA), tile 7 streamed from LDS (8 b128/wave/step,
// hoisted before the register-only MFMAs -> overlapped).
// A-operand: all lanes load the same 16B y-slice per k-quarter (broadcast);
// rows 1..15 of A/D are garbage and discarded (rows don't mix in MFMA).
// Raw barriers (lgkmcnt(0)+s_barrier, no vmcnt drain) keep the 2-step-ahead
// gx prefetch in flight across the step.
// Phase-split N (0..3 then 4..7) caps live acc at 16 regs: 224+16 <= 256 AGPR.
// Dynamic LDS: 65536 (ldsB) + 1024 (ypub) + 4096 (rawb) = 70656 B.
// ---------------------------------------------------------------------------
__global__ __launch_bounds__(512)
void slstm_scan5(
    const float* __restrict__ rk,    // (NH, DH, 4*DH)
    const float* __restrict__ rb,    // (NH, 4, DH)
    const __half* __restrict__ gx,   // [S][B][NH][1024]
    float* __restrict__ out)         // (B, S, E)
{
  extern __shared__ unsigned char smem[];
  uint4* ldsB  = (uint4*)smem;                 // [8w][8kt][64l] = 65536 B
  __half* ypub = (__half*)(smem + 65536);      // [2][256]
  float* rawb  = (float*)(smem + 66560);       // [1024]

  const int t = threadIdx.x;
  const int w = t >> 6, l = t & 63;
  const int lrow = l & 15, lkq = l >> 4;
  const int b = blockIdx.x >> 2, h = blockIdx.x & 3;
  const float* Rh = rk + (size_t)h * DHH * 1024;
  const int n0w = w << 7;

  // B-fragments for N-tiles 0..6 into registers (AGPR-resident)
  f16x8 wB[7][8];
#pragma unroll
  for (int nt = 0; nt < 7; ++nt) {
    const int col = n0w + nt * 16 + lrow;
#pragma unroll
    for (int kt = 0; kt < 8; ++kt) {
      f16x8 f;
#pragma unroll
      for (int i = 0; i < 4; ++i) {
        const int k = kt * 32 + lkq * 8 + 2 * i;
        f[2 * i]     = (_Float16)Rh[(size_t)k * 1024 + col];
        f[2 * i + 1] = (_Float16)Rh[(size_t)(k + 1) * 1024 + col];
      }
      wB[nt][kt] = f;
    }
  }
  // N-tile 7 into LDS, fragment order
  {
    const int col = n0w + 112 + lrow;
    for (int kt = 0; kt < 8; ++kt) {
      f16x8 f;
      for (int i = 0; i < 4; ++i) {
        const int k = kt * 32 + lkq * 8 + 2 * i;
        f[2 * i]     = (_Float16)Rh[(size_t)k * 1024 + col];
        f[2 * i + 1] = (_Float16)Rh[(size_t)(k + 1) * 1024 + col];
      }
      *(f16x8*)&ldsB[(w * 8 + kt) * 64 + l] = f;
    }
  }

  // state-thread setup (t < 256 owns dim d = t)
  const int d = t & 255;
  float rb0 = 0.f, rb1 = 0.f, rb2 = 0.f, rb3 = 0.f;
  if (t < 256) {
    rb0 = rb[h * 1024 + d];
    rb1 = rb[h * 1024 + 256 + d];
    rb2 = rb[h * 1024 + 512 + d];
    rb3 = rb[h * 1024 + 768 + d];
    ypub[d] = __float2half(0.f);
    ypub[256 + d] = __float2half(0.f);
  }
  __syncthreads();

  float cst = 0.f, nst = 0.f, mst = 0.f;
  const size_t gxstep = (size_t)BB * NHH * 1024;
  const __half* gp = gx + ((size_t)b * NHH + h) * 1024;
  // cx = step-0 inputs (f32); nh = step-1 inputs (f16)
  float cx0 = 0.f, cx1 = 0.f, cx2 = 0.f, cx3 = 0.f;
  __half nh0 = __float2half(0.f), nh1 = nh0, nh2 = nh0, nh3 = nh0;
  if (t < 256) {
    cx0 = __half2float(gp[d]);
    cx1 = __half2float(gp[256 + d]);
    cx2 = __half2float(gp[512 + d]);
    cx3 = __half2float(gp[768 + d]);
    const __half* p1 = gp + gxstep;
    nh0 = p1[d]; nh1 = p1[256 + d]; nh2 = p1[512 + d]; nh3 = p1[768 + d];
  }

  int cur = 0;
  for (int st = 0; st < SS; ++st) {
    // issue prefetch for step st+2 (stays in flight across raw barriers)
    __half p0 = nh0, p1 = nh1, p2 = nh2, p3 = nh3;
    if (t < 256) {
      const int sp = (st + 2 < SS) ? st + 2 : SS - 1;
      const __half* pp = gp + (size_t)sp * gxstep;
      p0 = pp[d]; p1 = pp[256 + d]; p2 = pp[512 + d]; p3 = pp[768 + d];
    }

    const __half* yc = ypub + cur * 256;
    // A fragments: every lane loads the same 16B y-slice of its k-quarter
    f16x8 Areg[8];
#pragma unroll
    for (int kt = 0; kt < 8; ++kt)
      Areg[kt] = *(const f16x8*)(yc + kt * 32 + lkq * 8);
    // hoisted LDS loads of tile-7 fragments
    f16x8 b7[8];
#pragma unroll
    for (int kt = 0; kt < 8; ++kt)
      b7[kt] = *(const f16x8*)&ldsB[(w * 8 + kt) * 64 + l];

    // phase 1: N-tiles 0..3 (register B only)
    {
      f32x4 a0 = {}, a1 = {}, a2 = {}, a3 = {};
#pragma unroll
      for (int kt = 0; kt < 8; ++kt) {
        a0 = __builtin_amdgcn_mfma_f32_16x16x32_f16(Areg[kt], wB[0][kt], a0, 0, 0, 0);
        a1 = __builtin_amdgcn_mfma_f32_16x16x32_f16(Areg[kt], wB[1][kt], a1, 0, 0, 0);
        a2 = __builtin_amdgcn_mfma_f32_16x16x32_f16(Areg[kt], wB[2][kt], a2, 0, 0, 0);
        a3 = __builtin_amdgcn_mfma_f32_16x16x32_f16(Areg[kt], wB[3][kt], a3, 0, 0, 0);
      }
      if (l < 16) {
        rawb[n0w +  0 + l] = a0[0];
        rawb[n0w + 16 + l] = a1[0];
        rawb[n0w + 32 + l] = a2[0];
        rawb[n0w + 48 + l] = a3[0];
      }
    }
    // phase 2: N-tiles 4..6 (register B) + tile 7 (LDS-staged b7)
    {
      f32x4 c0 = {}, c1 = {}, c2 = {}, c3 = {};
#pragma unroll
      for (int kt = 0; kt < 8; ++kt) {
        c0 = __builtin_amdgcn_mfma_f32_16x16x32_f16(Areg[kt], wB[4][kt], c0, 0, 0, 0);
        c1 = __builtin_amdgcn_mfma_f32_16x16x32_f16(Areg[kt], wB[5][kt], c1, 0, 0, 0);
        c2 = __builtin_amdgcn_mfma_f32_16x16x32_f16(Areg[kt], wB[6][kt], c2, 0, 0, 0);
        c3 = __builtin_amdgcn_mfma_f32_16x16x32_f16(Areg[kt], b7[kt],    c3, 0, 0, 0);
      }
      if (l < 16) {
        rawb[n0w +  64 + l] = c0[0];
        rawb[n0w +  80 + l] = c1[0];
        rawb[n0w +  96 + l] = c2[0];
        rawb[n0w + 112 + l] = c3[0];
      }
    }

    // b1: raw ready (LDS-only ordering; no vmcnt drain)
    asm volatile("s_waitcnt lgkmcnt(0)" ::: "memory");
    __builtin_amdgcn_s_barrier();

    if (t < 256) {
      float iv = rawb[d]       + cx0 + rb0;
      float fv = rawb[256 + d] + cx1 + rb1;
      float zv = rawb[512 + d] + cx2 + rb2;
      float ov = rawb[768 + d] + cx3 + rb3;

      float ea = __expf(-fabsf(fv));
      float ls = fminf(fv, 0.f) - __logf(1.f + ea);    // log_sigmoid(fv)
      float lfm = mst + ls;
      float mn = fmaxf(iv, lfm);
      float ig = __expf(iv - mn);
      float fg = __expf(lfm - mn);
      float pz = __expf(-2.f * fabsf(zv));
      float tm = __fdividef(1.f - pz, 1.f + pz);
      float th = (zv < 0.f) ? -tm : tm;                // tanh(zv)
      cst = fg * cst + ig * th;
      nst = fg * nst + ig;
      float og = __fdividef(1.f, 1.f + __expf(-ov));   // sigmoid(ov)
      float y = og * __fdividef(cst, nst);
      mst = mn;

      out[((size_t)b * SS + st) * EE + h * DHH + d] = y;
      ypub[(cur ^ 1) * 256 + d] = __float2half(y);
    }

    // b2: y ready
    asm volatile("s_waitcnt lgkmcnt(0)" ::: "memory");
    __builtin_amdgcn_s_barrier();

    cur ^= 1;
    cx0 = __half2float(nh0); cx1 = __half2float(nh1);
    cx2 = __half2float(nh2); cx3 = __half2float(nh3);
    nh0 = p0; nh1 = p1; nh2 = p2; nh3 = p3;
  }
}

// ---------------------------------------------------------------------------
// GroupNorm over DH per (b,s,h), in place on out. One wave = one head.
// ---------------------------------------------------------------------------
__global__ __launch_bounds__(256) void groupnorm(
    float* __restrict__ y, const float* __restrict__ gnw)
{
  const int row = blockIdx.x;
  const int t = threadIdx.x;
  float4 v = ((const float4*)y)[(size_t)row * 256 + t];
  float s = v.x + v.y + v.z + v.w;
  float q = v.x * v.x + v.y * v.y + v.z * v.z + v.w * v.w;
#pragma unroll
  for (int mask = 1; mask < 64; mask <<= 1) {
    s += __shfl_xor(s, mask, 64);
    q += __shfl_xor(q, mask, 64);
  }
  float mu = s * (1.f / 256.f);
  float var = q * (1.f / 256.f) - mu * mu;
  float rs = rsqrtf(var + 1e-5f);
  float4 g = ((const float4*)gnw)[t];
  float4 o;
  o.x = (v.x - mu) * rs * g.x;
  o.y = (v.y - mu) * rs * g.y;
  o.z = (v.z - mu) * rs * g.z;
  o.w = (v.w - mu) * rs * g.w;
  ((float4*)y)[(size_t)row * 256 + t] = o;
}

extern "C" void kernel_launch(void* const* d_in, const int* in_sizes, int n_in,
                              void* d_out, int out_size, void* d_ws, size_t ws_size,
                              hipStream_t stream) {
  const float* x      = (const float*)d_in[0];
  const float* conv_w = (const float*)d_in[1];
  const float* conv_b = (const float*)d_in[2];
  const float* fgw    = (const float*)d_in[3];
  const float* igw    = (const float*)d_in[4];
  const float* zgw    = (const float*)d_in[5];
  const float* ogw    = (const float*)d_in[6];
  const float* rk     = (const float*)d_in[7];
  const float* rb     = (const float*)d_in[8];
  const float* gnw    = (const float*)d_in[9];
  float* out = (float*)d_out;
  __half* gx = (__half*)d_ws;   // [S][B][NH][1024] f16 = 134217728 B

  dim3 g1(256, 8, 8);
  gates_gemm<<<g1, 256, 0, stream>>>(x, conv_w, conv_b, fgw, igw, zgw, ogw, gx);

  const int scan_lds = 65536 + 1024 + 4096;
  (void)hipFuncSetAttribute(reinterpret_cast<const void*>(slstm_scan5),
                            hipFuncAttributeMaxDynamicSharedMemorySize, scan_lds);
  slstm_scan5<<<32, 512, scan_lds, stream>>>(rk, rb, gx, out);

  groupnorm<<<BB * SS, 256, 0, stream>>>(out, gnw);
}